// Round 1
// baseline (73.543 us; speedup 1.0000x reference)
//
#include <hip/hip_runtime.h>
#include <stdint.h>

typedef _Float16 f16x8 __attribute__((ext_vector_type(8)));
typedef float    f32x4 __attribute__((ext_vector_type(4)));

#define H 56
#define W 56
#define C_IN 32
#define N_OUT 64
#define PR 58                 // padded rows, row = ih+1
#define PCOLS 58              // padded cols, col = iw+1 (0 and 57 are the zero pads)
#define XB_BLOCKS (16 * PR)   // 928 transpose blocks
#define NWF 9216              // wf dwords: 9 ij * 4 nt * 64 lane * 4 dw
#define XPAD_BYTES ((size_t)16 * PR * PCOLS * C_IN * 2)   // 3,444,736 B (256-aligned)

__device__ __forceinline__ float q16f(float v) { return (float)(_Float16)v; }

// merged prep: blocks [0,928) transpose x to channel-innermost f16 with zero
// padding; blocks [928,964) pack weights into MFMA A-fragment order.
__global__ __launch_bounds__(256) void prep_kernel(
    const float* __restrict__ x, const float* __restrict__ weight,
    _Float16* __restrict__ xpad, uint32_t* __restrict__ wf)
{
    const int nb  = blockIdx.x;
    const int tid = threadIdx.x;
    if (nb < XB_BLOCKS) {
        // one block = one (b,row): x[b][c][ih][iw] -> xpad[b][row][col][c]
        __shared__ _Float16 sT[PCOLS * 34];   // col stride 34 f16 (17 dw) kills conflicts
        const int b = nb / PR, row = nb % PR, ih = row - 1;
        const bool interior = (unsigned)ih < (unsigned)H;
        if (interior) {
            // zero only the two pad columns (cols 1..56 are fully overwritten)
            if (tid < 32) {
                int col = (tid >> 4) * 57, cd = tid & 15;
                ((uint32_t*)sT)[col * 17 + cd] = 0u;
            }
            __syncthreads();
            #pragma unroll
            for (int k = 0; k < 7; ++k) {       // 7*256 = 1792 = 32c * 56iw
                int idx = k * 256 + tid;
                int c = idx / W, iw = idx - c * W;
                sT[(iw + 1) * 34 + c] = (_Float16)x[((b * C_IN + c) * H + ih) * W + iw];
            }
        } else {
            // halo row: everything zero
            for (int i = tid; i < PCOLS * 17; i += 256) ((uint32_t*)sT)[i] = 0u;
        }
        __syncthreads();
        // write out 928 dwords as 464 coalesced uint2
        uint2* dst = (uint2*)(xpad + ((size_t)b * PR + row) * PCOLS * C_IN);
        for (int i = tid; i < PCOLS * 8; i += 256) {
            int col = i >> 3, cd2 = i & 7;
            const uint32_t* s = &((const uint32_t*)sT)[col * 17 + 2 * cd2];
            uint2 v = { s[0], s[1] };
            dst[i] = v;
        }
    } else {
        // A-frag pack: dword o = ((ij*4+nt)*64 + lane)*4 + t2
        // A[m = nt*16 + (lane&15) -> n][k = (lane>>4)*8 + 2*t2 + {0,1} -> c]
        int o = (nb - XB_BLOCKS) * 256 + tid;           // < 9216
        int t2   = o & 3;
        int lane = (o >> 2) & 63;
        int u    = o >> 8;
        int nt   = u & 3, ij = u >> 2;
        int n    = nt * 16 + (lane & 15);
        int c0   = (lane >> 4) * 8 + 2 * t2;
        _Float16 lo = (_Float16)weight[n * 288 + c0 * 9 + ij];
        _Float16 hi = (_Float16)weight[n * 288 + (c0 + 1) * 9 + ij];
        wf[o] = (uint32_t)__builtin_bit_cast(uint16_t, lo) |
                ((uint32_t)__builtin_bit_cast(uint16_t, hi) << 16);
    }
}

// conv as 9 shifted K=32 GEMMs, no LDS, no barrier.
// wave = 1 oh row x 32 ow (two 16-px B-frag groups sharing A) x 32 n (nt half).
// nt-split across blockIdx.z doubles resident waves (1.75 -> 3.5 blocks/CU)
// to hide the L2-latency of the wf/xpad fragment loads.
__global__ __launch_bounds__(256, 4) void conv_mfma(
    const _Float16* __restrict__ xpad,   // [16][58][58][32] f16
    const f16x8*    __restrict__ wf,     // A-fragment layout
    const float*    __restrict__ bias,   // [64]
    float* __restrict__ out)             // [16,64,56,56]
{
    const int tid  = threadIdx.x;
    const int bz   = blockIdx.z;
    const int b    = bz >> 1;            // batch
    const int nh   = bz & 1;             // nt half: nt = nh*2 + t, t in {0,1}
    const int oh   = blockIdx.y * 4 + (tid >> 6);
    const int bx   = blockIdx.x;
    const int ow0  = bx * 24;            // tiles cover ow 0-31 and 24-55
    const int lane = tid & 63;
    const int quad = lane >> 4;
    const int px   = lane & 15;

    // B-frag bases: B[k=c][n=px], k = quad*8+t -> 16 contiguous bytes per load
    const _Float16* xb0 = xpad + (((size_t)b * PR + oh) * PCOLS + ow0 + px) * C_IN + quad * 8;
    const _Float16* xb1 = xb0 + 16 * C_IN;

    f32x4 acc[2][2] = {{{0,0,0,0},{0,0,0,0}},
                       {{0,0,0,0},{0,0,0,0}}};

    #pragma unroll
    for (int ij = 0; ij < 9; ++ij) {
        const int i = ij / 3, jj = ij - 3 * i;
        const int sh = (i * PCOLS + jj) * C_IN;
        f16x8 xf0 = *(const f16x8*)(xb0 + sh);              // dwordx4, L1/L2-hot
        f16x8 xf1 = *(const f16x8*)(xb1 + sh);
        #pragma unroll
        for (int t = 0; t < 2; ++t) {
            const int nt = nh * 2 + t;
            f16x8 wv = wf[(ij * 4 + nt) * 64 + lane];       // dwordx4, L2-hot
            acc[0][t] = __builtin_amdgcn_mfma_f32_16x16x32_f16(wv, xf0, acc[0][t], 0, 0, 0);
            acc[1][t] = __builtin_amdgcn_mfma_f32_16x16x32_f16(wv, xf1, acc[1][t], 0, 0, 0);
        }
    }

    // epilogue: out = q16(acc + q16(bias)); quarter-wave = one full 64B line.
    // overlap columns 24..31 are owned by tile bx==0.
    float qb[2][4];
    #pragma unroll
    for (int t = 0; t < 2; ++t)
        #pragma unroll
        for (int reg = 0; reg < 4; ++reg)
            qb[t][reg] = q16f(bias[(nh * 2 + t) * 16 + quad * 4 + reg]);

    #pragma unroll
    for (int xg = 0; xg < 2; ++xg) {
        const int ow = ow0 + 16 * xg + px;
        if (bx == 0 || ow >= 32) {
            #pragma unroll
            for (int t = 0; t < 2; ++t) {
                #pragma unroll
                for (int reg = 0; reg < 4; ++reg) {
                    const int n = (nh * 2 + t) * 16 + quad * 4 + reg;
                    out[((size_t)(b * N_OUT + n) * H + oh) * W + ow] =
                        q16f(acc[xg][t][reg] + qb[t][reg]);
                }
            }
        }
    }
}

extern "C" void kernel_launch(void* const* d_in, const int* in_sizes, int n_in,
                              void* d_out, int out_size, void* d_ws, size_t ws_size,
                              hipStream_t stream) {
    const float* x      = (const float*)d_in[0];
    const float* weight = (const float*)d_in[1];
    const float* bias   = (const float*)d_in[2];
    float* out          = (float*)d_out;

    _Float16* xpad = (_Float16*)d_ws;
    uint32_t* wfp  = (uint32_t*)((char*)d_ws + XPAD_BYTES);   // 36,864 B

    prep_kernel<<<dim3(XB_BLOCKS + NWF / 256), dim3(256), 0, stream>>>(x, weight, xpad, wfp);
    conv_mfma<<<dim3(2, 14, 32), dim3(256), 0, stream>>>(xpad, (const f16x8*)wfp, bias, out);
}